// Round 10
// baseline (317.904 us; speedup 1.0000x reference)
//
#include <hip/hip_runtime.h>
#include <hip/hip_bf16.h>

using f32x4  = __attribute__((ext_vector_type(4))) float;
using bf16x8 = __attribute__((ext_vector_type(8))) short;
using s16x4  = __attribute__((ext_vector_type(4))) short;

constexpr int kB  = 8;
constexpr int kA  = 32;
constexpr int kT  = 64;
constexpr int kNH = 256;
constexpr int kNE = 256;                 // NEMB
constexpr int kE  = kA * (kA - 1);       // 992
constexpr int kM  = kB * kA * kT;        // 16384 rows of h
constexpr int kK  = kNH;                 // 256
constexpr int kN  = 2 * kNE;             // 512 (Ps | Pr)

// flag indices (unsigned int array, zeroed by hipMemsetAsync each launch)
constexpr int FW = 0;                    // W-split done counter  (target 512)
constexpr int FL = 1;                    // LUT done counter      (target 4)
constexpr int FA = 2;                    // aflag[128]            (target 4 each)
constexpr int FP = 130;                  // pflag[128]            (target 4 each)

__device__ __forceinline__ unsigned short rne_bf16(float f) {
    unsigned int u = __float_as_uint(f);
    u += 0x7fffu + ((u >> 16) & 1u);
    return (unsigned short)(u >> 16);
}
__device__ __forceinline__ float bf16_f32(unsigned short h) {
    return __uint_as_float(((unsigned int)h) << 16);
}
// 2-way split: x ~= hi + mid (each bf16), residual <= 2^-17 |x|
__device__ __forceinline__ void split2(float x, unsigned short& h, unsigned short& m) {
    h = rne_bf16(x);
    float r1 = x - bf16_f32(h);
    m = rne_bf16(r1);
}

#define GLL(g, l) __builtin_amdgcn_global_load_lds( \
    (const __attribute__((address_space(1))) void*)(g), \
    (__attribute__((address_space(3))) void*)(l), 16, 0, 0)

#define FLAG_ADD(i) __hip_atomic_fetch_add(&flags[i], 1u, __ATOMIC_RELEASE, \
                                           __HIP_MEMORY_SCOPE_AGENT)
#define FLAG_WAIT(i, tgt)                                                        \
    while (__hip_atomic_load(&flags[i], __ATOMIC_ACQUIRE,                        \
                             __HIP_MEMORY_SCOPE_AGENT) < (unsigned)(tgt))        \
        __builtin_amdgcn_s_sleep(2)

// ============================================================================
// Single REGULAR-launch kernel (cooperative launch proven broken in harness:
// R8/R9 both produced all-zero output). 512 blocks x 256 thr, 32KB LDS,
// __launch_bounds__(256,2): every CU can host >=2 blocks (LDS alone allows 5),
// so ALL 512 blocks are co-resident -> flag spin-waits always progress.
// DAG: S (split, no deps) -> {aflag,wdone,lutflag} -> G (GEMM) -> pflag -> R
// (gather). All bulk producer->consumer flow is same-XCD (bid&7 pinning);
// flags use agent-scope release/acquire atomics + __threadfence.
// ============================================================================
__global__ __launch_bounds__(256, 2) void k_all(const float* __restrict__ hsrc,
                                                const float* __restrict__ W,
                                                const float* __restrict__ rel_rec,
                                                const float* __restrict__ rel_send,
                                                const float* __restrict__ bias,
                                                unsigned short* __restrict__ a1,
                                                unsigned short* __restrict__ a2,
                                                unsigned short* __restrict__ b1,
                                                unsigned short* __restrict__ b2,
                                                float* __restrict__ P,
                                                int* __restrict__ ij2e,
                                                unsigned int* flags,
                                                float* __restrict__ out) {
    __shared__ unsigned short sAh[128 * 32], sAm[128 * 32];   // 8 KB each
    __shared__ unsigned short sBh[128 * 32], sBm[128 * 32];   // total 32768 B

    const int bid = blockIdx.x;              // 0..511
    const int tid = threadIdx.x;
    const int xcd = bid & 7;
    const int idx = bid >> 3;                // 0..63
    const int bn  = idx & 3;
    const int bm  = xcd * 16 + (idx >> 2);   // batch = xcd

    // -------------------- phase S: split --------------------
    {
        // A-split: this block's 32 rows of its own GEMM tile (4 siblings/tile)
        const int row0 = bm * 128 + bn * 32;
        const size_t base4 = (size_t)row0 * 64;         // f32x4 units (256 f32/row)
#pragma unroll
        for (int r = 0; r < 8; ++r) {
            size_t i4 = base4 + (size_t)r * 256 + tid;
            f32x4 v = ((const f32x4*)hsrc)[i4];
            s16x4 o1, o2;
#pragma unroll
            for (int j = 0; j < 4; ++j) {
                unsigned short h, m;
                split2(v[j], h, m);
                o1[j] = (short)h; o2[j] = (short)m;
            }
            *(s16x4*)(a1 + i4 * 4) = o1;
            *(s16x4*)(a2 + i4 * 4) = o2;
        }
        // W-split: block bid handles B^T row n=bid (256 k-elems, 1/thread)
        float wv = (bid < kNE) ? W[(size_t)bid * (2 * kNH) + tid]
                               : W[(size_t)(bid - kNE) * (2 * kNH) + kNH + tid];
        unsigned short wh, wm;
        split2(wv, wh, wm);
        b1[(size_t)bid * kK + tid] = wh;
        b2[(size_t)bid * kK + tid] = wm;
        // edge LUT: blocks 0..3
        if (bid < 4) {
            int e = bid * 256 + tid;
            if (e < kE) {
                int ir = 0, is = 0;
                for (int a = 0; a < kA; ++a) {
                    if (rel_rec[(size_t)e * kA + a]  > 0.5f) ir = a;
                    if (rel_send[(size_t)e * kA + a] > 0.5f) is = a;
                }
                ij2e[is * kA + ir] = e;
            }
        }
        __threadfence();
        __syncthreads();
        if (tid == 0) {
            FLAG_ADD(FA + bm);
            FLAG_ADD(FW);
            if (bid < 4) FLAG_ADD(FL);
        }
    }

    // -------------------- phase G: GEMM --------------------
    {
        if (tid == 0) { FLAG_WAIT(FA + bm, 4); FLAG_WAIT(FW, 512); }
        __syncthreads();

        const int lane = tid & 63;
        const int wave = tid >> 6;
        const int wr = wave >> 1, wc = wave & 1;

        const int sr   = tid >> 2;                      // row within 64-row half-tile
        const int scb  = (tid & 3) << 4;                // byte col within 64B row
        const int scbs = scb ^ (((sr >> 1) & 3) << 4);  // pre-swizzled source col
        const size_t rA  = (size_t)(bm * 128 + sr) * kK + (scbs >> 1);
        const size_t rB  = (size_t)(bn * 128 + sr) * kK + (scbs >> 1);
        const size_t rA1 = rA + (size_t)64 * kK;
        const size_t rB1 = rB + (size_t)64 * kK;
        const int l0 = tid * 8, l1 = 64 * 32 + tid * 8;

        const int fr  = lane & 15;
        const int fkb = (lane >> 4) << 4;
        const int swz = ((fr >> 1) & 3) << 4;

        f32x4 acc[4][4] = {};

#pragma unroll
        for (int kt = 0; kt < 8; ++kt) {
            const int kk = kt * 32;
            __syncthreads();                 // previous compute done
            GLL(a1 + rA + kk, sAh + l0);  GLL(a1 + rA1 + kk, sAh + l1);
            GLL(a2 + rA + kk, sAm + l0);  GLL(a2 + rA1 + kk, sAm + l1);
            GLL(b1 + rB + kk, sBh + l0);  GLL(b1 + rB1 + kk, sBh + l1);
            GLL(b2 + rB + kk, sBm + l0);  GLL(b2 + rB1 + kk, sBm + l1);
            __syncthreads();                 // drain staging

            bf16x8 ah[4], am[4], bh[4], bmf[4];
#pragma unroll
            for (int mi = 0; mi < 4; ++mi) {
                int row = wr * 64 + mi * 16 + fr;
                int off = row * 64 + (fkb ^ swz);
                ah[mi] = *(const bf16x8*)((const char*)sAh + off);
                am[mi] = *(const bf16x8*)((const char*)sAm + off);
            }
#pragma unroll
            for (int ni = 0; ni < 4; ++ni) {
                int row = wc * 64 + ni * 16 + fr;
                int off = row * 64 + (fkb ^ swz);
                bh[ni]  = *(const bf16x8*)((const char*)sBh + off);
                bmf[ni] = *(const bf16x8*)((const char*)sBm + off);
            }
#pragma unroll
            for (int mi = 0; mi < 4; ++mi)
#pragma unroll
                for (int ni = 0; ni < 4; ++ni) {
                    f32x4 c = acc[mi][ni];
                    c = __builtin_amdgcn_mfma_f32_16x16x32_bf16(ah[mi], bh[ni],  c, 0, 0, 0);
                    c = __builtin_amdgcn_mfma_f32_16x16x32_bf16(ah[mi], bmf[ni], c, 0, 0, 0);
                    c = __builtin_amdgcn_mfma_f32_16x16x32_bf16(am[mi], bh[ni],  c, 0, 0, 0);
                    acc[mi][ni] = c;
                }
        }

        // epilogue: C/D layout col=lane&15, row=(lane>>4)*4+r  [m89-verified]
        const int col = lane & 15;
        const int rb  = (lane >> 4) << 2;
#pragma unroll
        for (int mi = 0; mi < 4; ++mi)
#pragma unroll
            for (int ni = 0; ni < 4; ++ni) {
                int n = bn * 128 + wc * 64 + ni * 16 + col;
#pragma unroll
                for (int r = 0; r < 4; ++r) {
                    int m = bm * 128 + wr * 64 + mi * 16 + rb + r;
                    P[(size_t)m * kN + n] = acc[mi][ni][r];
                }
            }
        __threadfence();
        __syncthreads();
        if (tid == 0) FLAG_ADD(FP + bm);
    }

    // -------------------- phase R: gather --------------------
    {
        const int b  = bid & 7;              // same XCD that produced P[b]
        const int gi = (bid >> 3) & 7;
        const int gj = (bid >> 6) & 7;
        const int m0 = b * 16 + 2 * gi;      // needed P tiles
        const int m2 = b * 16 + 2 * gj;
        if (tid == 0) {
            FLAG_WAIT(FL, 4);
            FLAG_WAIT(FP + m0, 4);  FLAG_WAIT(FP + m0 + 1, 4);
            FLAG_WAIT(FP + m2, 4);  FLAG_WAIT(FP + m2 + 1, 4);
        }
        __syncthreads();

        int* se = (int*)sAh;                 // alias GEMM LDS (free now)
        if (tid < 16) {
            int si = tid >> 2, rj = tid & 3;
            int i = gi * 4 + si, j = gj * 4 + rj;
            se[tid] = (i == j) ? -1 : ij2e[i * kA + j];
        }
        __syncthreads();
        int e[16];
#pragma unroll
        for (int k = 0; k < 16; ++k) e[k] = se[k];

        const int c = tid & 63;              // f32x4 col 0..63
        const int w = tid >> 6;
        f32x4 bv = ((const f32x4*)bias)[c];
        const float* Pb = P + (size_t)(b * kA) * kT * kN;
        float* outb = out + (size_t)b * kE * kT * kNE;

        for (int i = 0; i < 16; ++i) {
            int t = w + i * 4;
            f32x4 ps[4], pr[4];
#pragma unroll
            for (int si = 0; si < 4; ++si)
                ps[si] = *(const f32x4*)(Pb + ((size_t)(gi * 4 + si) * kT + t) * kN + c * 4);
#pragma unroll
            for (int rj = 0; rj < 4; ++rj)
                pr[rj] = *(const f32x4*)(Pb + ((size_t)(gj * 4 + rj) * kT + t) * kN + kNE + c * 4);
#pragma unroll
            for (int si = 0; si < 4; ++si)
#pragma unroll
                for (int rj = 0; rj < 4; ++rj) {
                    int ee = e[si * 4 + rj];
                    if (ee >= 0) {
                        f32x4 v = ps[si] + pr[rj] + bv;
                        __builtin_nontemporal_store(
                            v, (f32x4*)(outb + ((size_t)ee * kT + t) * kNE + c * 4));
                    }
                }
        }
    }
}

extern "C" void kernel_launch(void* const* d_in, const int* in_sizes, int n_in,
                              void* d_out, int out_size, void* d_ws, size_t ws_size,
                              hipStream_t stream) {
    const float* h    = (const float*)d_in[0];
    const float* rrec = (const float*)d_in[1];
    const float* rsnd = (const float*)d_in[2];
    const float* W    = (const float*)d_in[3];
    const float* bias = (const float*)d_in[4];
    float* out = (float*)d_out;

    char* ws = (char*)d_ws;
    const size_t MB = 1024 * 1024;
    unsigned short* Ah = (unsigned short*)(ws);                  // 8 MB
    unsigned short* Am = (unsigned short*)(ws + 8 * MB);         // 8 MB
    unsigned short* Bh = (unsigned short*)(ws + 16 * MB);        // 256 KB
    unsigned short* Bm = (unsigned short*)(ws + 16 * MB + 256 * 1024);
    float* P   = (float*)(ws + 17 * MB);                         // 32 MB
    int* ij2e  = (int*)(ws + 49 * MB);                           // 4 KB
    unsigned int* flags = (unsigned int*)(ws + 49 * MB + 4096);  // 1032 B used

    hipMemsetAsync(flags, 0, 4096, stream);
    k_all<<<dim3(512), dim3(256), 0, stream>>>(h, W, rrec, rsnd, bias,
                                               Ah, Am, Bh, Bm, P, ij2e, flags, out);
}

// Round 11
// 129.734 us; speedup vs baseline: 2.4504x; 2.4504x over previous
//
#include <hip/hip_runtime.h>
#include <hip/hip_bf16.h>

using f32x4  = __attribute__((ext_vector_type(4))) float;
using bf16x8 = __attribute__((ext_vector_type(8))) short;
using s16x4  = __attribute__((ext_vector_type(4))) short;

constexpr int kB  = 8;
constexpr int kA  = 32;
constexpr int kT  = 64;
constexpr int kNH = 256;
constexpr int kNE = 256;                 // NEMB
constexpr int kE  = kA * (kA - 1);       // 992
constexpr int kM  = kB * kA * kT;        // 16384 rows of h
constexpr int kK  = kNH;                 // 256
constexpr int kN  = 2 * kNE;             // 512 (Ps | Pr)

__device__ __forceinline__ unsigned short rne_bf16(float f) {
    unsigned int u = __float_as_uint(f);
    u += 0x7fffu + ((u >> 16) & 1u);
    return (unsigned short)(u >> 16);
}
__device__ __forceinline__ float bf16_f32(unsigned short h) {
    return __uint_as_float(((unsigned int)h) << 16);
}
// 2-way split: x ~= hi + mid (each bf16), residual <= 2^-17 |x|
__device__ __forceinline__ void split2(float x, unsigned short& h, unsigned short& m) {
    h = rne_bf16(x);
    float r1 = x - bf16_f32(h);
    m = rne_bf16(r1);
}

#define GLL(g, l) __builtin_amdgcn_global_load_lds( \
    (const __attribute__((address_space(1))) void*)(g), \
    (__attribute__((address_space(3))) void*)(l), 16, 0, 0)

// flags: 64B-strided slots. aflag[bm]=slot bm, pflag[bm]=slot 128+bm,
// fw[xcd]=slot 256+xcd, fl[xcd]=slot 264+xcd. RELAXED atomics only:
// R10's ACQUIRE-polling emitted buffer_inv (L2 invalidate) per poll ->
// L2 thrash -> 318us. All bulk data flows are same-XCD (L2 = coherence
// point); consumer CUs never read those addresses before (no stale L1);
// vector L1 is write-through. Producers drain stores via the implicit
// s_waitcnt of __syncthreads() BEFORE tid0 bumps the flag.
#define FLAG_ADD(slot) __hip_atomic_fetch_add(&flags[(slot) * 16], 1u, \
    __ATOMIC_RELAXED, __HIP_MEMORY_SCOPE_AGENT)
#define FLAG_WAIT(slot, tgt)                                                   \
    while (__hip_atomic_load(&flags[(slot) * 16], __ATOMIC_RELAXED,            \
                             __HIP_MEMORY_SCOPE_AGENT) < (unsigned)(tgt))      \
        __builtin_amdgcn_s_sleep(1)

// ============================================================================
// Single regular-launch fused kernel. 512 blocks x 256 thr, 32KB LDS,
// __launch_bounds__(256,2): >=2 blocks/CU -> all 512 co-resident -> spin
// waits always progress. DAG: S (split; A rows of own tile, W+LUT duplicated
// PER XCD so every flow is same-XCD) -> G (GEMM, 3-term split-bf16) -> R
// (gather, 4x4 atom-group, nontemporal stores). XCD x owns batch x end-to-end.
// ============================================================================
__global__ __launch_bounds__(256, 2) void k_all(const float* __restrict__ hsrc,
                                                const float* __restrict__ W,
                                                const float* __restrict__ rel_rec,
                                                const float* __restrict__ rel_send,
                                                const float* __restrict__ bias,
                                                unsigned short* __restrict__ a1,
                                                unsigned short* __restrict__ a2,
                                                unsigned short* __restrict__ b1,
                                                unsigned short* __restrict__ b2,
                                                float* __restrict__ P,
                                                int* __restrict__ ij2e,
                                                unsigned int* flags,
                                                float* __restrict__ out) {
    __shared__ unsigned short sAh[128 * 32], sAm[128 * 32];   // 8 KB each
    __shared__ unsigned short sBh[128 * 32], sBm[128 * 32];   // total 32768 B

    const int bid = blockIdx.x;              // 0..511
    const int tid = threadIdx.x;
    const int xcd = bid & 7;
    const int idx = bid >> 3;                // 0..63
    const int bn  = idx & 3;
    const int bm  = xcd * 16 + (idx >> 2);   // batch = xcd

    // per-XCD copies of the B (W-split) panels and edge LUT
    unsigned short* b1x = b1 + (size_t)xcd * (kN * kK);
    unsigned short* b2x = b2 + (size_t)xcd * (kN * kK);
    int*            lut = ij2e + xcd * 1024;

    // -------------------- phase S: split --------------------
    {
        // A-split: this block's 32 rows of its own GEMM tile (4 siblings/tile)
        const int row0 = bm * 128 + bn * 32;
        const size_t base4 = (size_t)row0 * 64;         // f32x4 units (256 f32/row)
#pragma unroll
        for (int r = 0; r < 8; ++r) {
            size_t i4 = base4 + (size_t)r * 256 + tid;
            f32x4 v = ((const f32x4*)hsrc)[i4];
            s16x4 o1, o2;
#pragma unroll
            for (int j = 0; j < 4; ++j) {
                unsigned short h, m;
                split2(v[j], h, m);
                o1[j] = (short)h; o2[j] = (short)m;
            }
            *(s16x4*)(a1 + i4 * 4) = o1;
            *(s16x4*)(a2 + i4 * 4) = o2;
        }
        // W-split into THIS XCD's copy: block idx handles B^T rows idx*8..+7
#pragma unroll
        for (int r = 0; r < 8; ++r) {
            int n = idx * 8 + r;             // 0..511
            float wv = (n < kNE) ? W[(size_t)n * (2 * kNH) + tid]
                                 : W[(size_t)(n - kNE) * (2 * kNH) + kNH + tid];
            unsigned short wh, wm;
            split2(wv, wh, wm);
            b1x[(size_t)n * kK + tid] = wh;
            b2x[(size_t)n * kK + tid] = wm;
        }
        // edge LUT into THIS XCD's copy: blocks idx 0..3
        if (idx < 4) {
            int e = idx * 256 + tid;
            if (e < kE) {
                int ir = 0, is = 0;
                for (int a = 0; a < kA; ++a) {
                    if (rel_rec[(size_t)e * kA + a]  > 0.5f) ir = a;
                    if (rel_send[(size_t)e * kA + a] > 0.5f) is = a;
                }
                lut[is * kA + ir] = e;
            }
        }
        __syncthreads();                     // drains all waves' stores (vmcnt)
        if (tid == 0) {
            FLAG_ADD(bm);                    // aflag
            FLAG_ADD(256 + xcd);             // fw (target 64)
            if (idx < 4) FLAG_ADD(264 + xcd);// fl (target 4)
        }
    }

    // -------------------- phase G: GEMM --------------------
    {
        if (tid == 0) { FLAG_WAIT(bm, 4); FLAG_WAIT(256 + xcd, 64); }
        __syncthreads();
        asm volatile("" ::: "memory");

        const int lane = tid & 63;
        const int wave = tid >> 6;
        const int wr = wave >> 1, wc = wave & 1;

        const int sr   = tid >> 2;                      // row within 64-row half-tile
        const int scb  = (tid & 3) << 4;                // byte col within 64B row
        const int scbs = scb ^ (((sr >> 1) & 3) << 4);  // pre-swizzled source col
        const size_t rA  = (size_t)(bm * 128 + sr) * kK + (scbs >> 1);
        const size_t rB  = (size_t)(bn * 128 + sr) * kK + (scbs >> 1);
        const size_t rA1 = rA + (size_t)64 * kK;
        const size_t rB1 = rB + (size_t)64 * kK;
        const int l0 = tid * 8, l1 = 64 * 32 + tid * 8;

        const int fr  = lane & 15;
        const int fkb = (lane >> 4) << 4;
        const int swz = ((fr >> 1) & 3) << 4;

        f32x4 acc[4][4] = {};

#pragma unroll
        for (int kt = 0; kt < 8; ++kt) {
            const int kk = kt * 32;
            __syncthreads();                 // previous compute done
            GLL(a1  + rA + kk, sAh + l0);  GLL(a1  + rA1 + kk, sAh + l1);
            GLL(a2  + rA + kk, sAm + l0);  GLL(a2  + rA1 + kk, sAm + l1);
            GLL(b1x + rB + kk, sBh + l0);  GLL(b1x + rB1 + kk, sBh + l1);
            GLL(b2x + rB + kk, sBm + l0);  GLL(b2x + rB1 + kk, sBm + l1);
            __syncthreads();                 // drain staging

            bf16x8 ah[4], am[4], bh[4], bmf[4];
#pragma unroll
            for (int mi = 0; mi < 4; ++mi) {
                int row = wr * 64 + mi * 16 + fr;
                int off = row * 64 + (fkb ^ swz);
                ah[mi] = *(const bf16x8*)((const char*)sAh + off);
                am[mi] = *(const bf16x8*)((const char*)sAm + off);
            }
#pragma unroll
            for (int ni = 0; ni < 4; ++ni) {
                int row = wc * 64 + ni * 16 + fr;
                int off = row * 64 + (fkb ^ swz);
                bh[ni]  = *(const bf16x8*)((const char*)sBh + off);
                bmf[ni] = *(const bf16x8*)((const char*)sBm + off);
            }
#pragma unroll
            for (int mi = 0; mi < 4; ++mi)
#pragma unroll
                for (int ni = 0; ni < 4; ++ni) {
                    f32x4 c = acc[mi][ni];
                    c = __builtin_amdgcn_mfma_f32_16x16x32_bf16(ah[mi], bh[ni],  c, 0, 0, 0);
                    c = __builtin_amdgcn_mfma_f32_16x16x32_bf16(ah[mi], bmf[ni], c, 0, 0, 0);
                    c = __builtin_amdgcn_mfma_f32_16x16x32_bf16(am[mi], bh[ni],  c, 0, 0, 0);
                    acc[mi][ni] = c;
                }
        }

        // epilogue: C/D layout col=lane&15, row=(lane>>4)*4+r  [m89-verified]
        const int col = lane & 15;
        const int rb  = (lane >> 4) << 2;
#pragma unroll
        for (int mi = 0; mi < 4; ++mi)
#pragma unroll
            for (int ni = 0; ni < 4; ++ni) {
                int n = bn * 128 + wc * 64 + ni * 16 + col;
#pragma unroll
                for (int r = 0; r < 4; ++r) {
                    int m = bm * 128 + wr * 64 + mi * 16 + rb + r;
                    P[(size_t)m * kN + n] = acc[mi][ni][r];
                }
            }
        __syncthreads();                     // drains P stores (vmcnt)
        if (tid == 0) FLAG_ADD(128 + bm);    // pflag
    }

    // -------------------- phase R: gather --------------------
    {
        const int b  = xcd;                  // same XCD that produced P[b]
        const int gi = (bid >> 3) & 7;
        const int gj = (bid >> 6) & 7;
        const int m0 = b * 16 + 2 * gi;      // needed P tiles
        const int m2 = b * 16 + 2 * gj;
        if (tid == 0) {
            FLAG_WAIT(264 + xcd, 4);         // LUT ready
            FLAG_WAIT(128 + m0, 4);  FLAG_WAIT(128 + m0 + 1, 4);
            FLAG_WAIT(128 + m2, 4);  FLAG_WAIT(128 + m2 + 1, 4);
        }
        __syncthreads();
        asm volatile("" ::: "memory");

        int* se = (int*)sAh;                 // alias GEMM LDS (free now)
        if (tid < 16) {
            int si = tid >> 2, rj = tid & 3;
            int i = gi * 4 + si, j = gj * 4 + rj;
            se[tid] = (i == j) ? -1 : lut[i * kA + j];
        }
        __syncthreads();
        int e[16];
#pragma unroll
        for (int k = 0; k < 16; ++k) e[k] = se[k];

        const int c = tid & 63;              // f32x4 col 0..63
        const int w = tid >> 6;
        f32x4 bv = ((const f32x4*)bias)[c];
        const float* Pb = P + (size_t)(b * kA) * kT * kN;
        float* outb = out + (size_t)b * kE * kT * kNE;

        for (int i = 0; i < 16; ++i) {
            int t = w + i * 4;
            f32x4 ps[4], pr[4];
#pragma unroll
            for (int si = 0; si < 4; ++si)
                ps[si] = *(const f32x4*)(Pb + ((size_t)(gi * 4 + si) * kT + t) * kN + c * 4);
#pragma unroll
            for (int rj = 0; rj < 4; ++rj)
                pr[rj] = *(const f32x4*)(Pb + ((size_t)(gj * 4 + rj) * kT + t) * kN + kNE + c * 4);
#pragma unroll
            for (int si = 0; si < 4; ++si)
#pragma unroll
                for (int rj = 0; rj < 4; ++rj) {
                    int ee = e[si * 4 + rj];
                    if (ee >= 0) {
                        f32x4 v = ps[si] + pr[rj] + bv;
                        __builtin_nontemporal_store(
                            v, (f32x4*)(outb + ((size_t)ee * kT + t) * kNE + c * 4));
                    }
                }
        }
    }
}

extern "C" void kernel_launch(void* const* d_in, const int* in_sizes, int n_in,
                              void* d_out, int out_size, void* d_ws, size_t ws_size,
                              hipStream_t stream) {
    const float* h    = (const float*)d_in[0];
    const float* rrec = (const float*)d_in[1];
    const float* rsnd = (const float*)d_in[2];
    const float* W    = (const float*)d_in[3];
    const float* bias = (const float*)d_in[4];
    float* out = (float*)d_out;

    char* ws = (char*)d_ws;
    const size_t MB = 1024 * 1024;
    unsigned short* Ah = (unsigned short*)(ws);                  // 8 MB
    unsigned short* Am = (unsigned short*)(ws + 8 * MB);         // 8 MB
    unsigned short* Bh = (unsigned short*)(ws + 16 * MB);        // 8 x 256 KB = 2 MB
    unsigned short* Bm = (unsigned short*)(ws + 18 * MB);        // 2 MB
    float* P   = (float*)(ws + 20 * MB);                         // 32 MB
    int* ij2e  = (int*)(ws + 52 * MB);                           // 8 x 4 KB
    unsigned int* flags = (unsigned int*)(ws + 52 * MB + 64 * 1024);  // ~17.4 KB

    hipMemsetAsync(flags, 0, 32 * 1024, stream);
    k_all<<<dim3(512), dim3(256), 0, stream>>>(h, W, rrec, rsnd, bias,
                                               Ah, Am, Bh, Bm, P, ij2e, flags, out);
}